// Round 6
// baseline (231.629 us; speedup 1.0000x reference)
//
#include <hip/hip_runtime.h>

#define T_LEN 12
#define B_N   32768
#define H_N   128
#define BM    64    // batch rows per block

typedef __attribute__((ext_vector_type(8))) __bf16 bf16x8;
typedef __attribute__((ext_vector_type(8))) short  short8v;
typedef __attribute__((ext_vector_type(4))) float  f32x4;

__device__ __forceinline__ unsigned short f2bf(float f) {
  unsigned int u = __builtin_bit_cast(unsigned int, f);
  u += 0x7fffu + ((u >> 16) & 1u);
  return (unsigned short)(u >> 16);
}
__device__ __forceinline__ float sigm(float x) {
  return __builtin_amdgcn_rcpf(1.f + __builtin_amdgcn_exp2f(-1.4426950408889634f * x));
}
__device__ __forceinline__ float tanh_(float x) {
  return 1.f - 2.f * __builtin_amdgcn_rcpf(__builtin_amdgcn_exp2f(2.8853900817779268f * x) + 1.f);
}

// Fused weights in MFMA B-fragment order.
//   Wf[512][128] = Whh + (Wih@Wse01)@Whp (bf16): gates i,f -> WfReg ; gates g,o -> WfGO
//   G[512][2] = Wih@Wse01 ; u[512] = Wih@wse2 ; w0[512] = bih+bhh+Wih@bse+G@bhp
//   pBg: B-frags of Whp^T (cols 0,1 real, rest zero)
__global__ void prep_kernel(const float* __restrict__ Wih, const float* __restrict__ Whh,
                            const float* __restrict__ bih, const float* __restrict__ bhh,
                            const float* __restrict__ Wse, const float* __restrict__ bse,
                            const float* __restrict__ Whp, const float* __restrict__ bhp,
                            unsigned short* __restrict__ WfReg, unsigned short* __restrict__ WfGO,
                            unsigned short* __restrict__ pBg, float* __restrict__ u,
                            float* __restrict__ w0, float* __restrict__ G) {
  int i = blockIdx.x * 256 + threadIdx.x;
  if (i < 65536) {                      // one fused Wf element (row,k)
    int row = i >> 7, k = i & 127;
    float s = Whh[row * 128 + k];
    float wh0 = Whp[k], wh1 = Whp[128 + k];
    for (int e = 0; e < 64; ++e)
      s += Wih[row * 64 + e] * (Wse[e * 3 + 0] * wh0 + Wse[e * 3 + 1] * wh1);
    unsigned short v = f2bf(s);
    int g = row >> 7, unit = row & 127, w = unit >> 4, l15 = unit & 15;
    int ks = k >> 5, kg = (k >> 3) & 3, j = k & 7, l = kg * 16 + l15;
    if (g < 2) WfReg[((g * 4 + ks) * 512 + w * 64 + l) * 8 + j] = v;
    else       WfGO[(((g - 2) * 4 + ks) * 512 + w * 64 + l) * 8 + j] = v;
  } else if (i < 65536 + 2048) {        // u / w0 / G
    int j = i - 65536;
    int n = j >> 2, which = j & 3;
    float s = 0.f;
    if (which < 2) {
      for (int e = 0; e < 64; ++e) s += Wih[n * 64 + e] * Wse[e * 3 + which];
      G[n * 2 + which] = s;
    } else if (which == 2) {
      for (int e = 0; e < 64; ++e) s += Wih[n * 64 + e] * Wse[e * 3 + 2];
      u[n] = s;
    } else {
      for (int e = 0; e < 64; ++e)
        s += Wih[n * 64 + e] * (bse[e] + Wse[e * 3 + 0] * bhp[0] + Wse[e * 3 + 1] * bhp[1]);
      w0[n] = bih[n] + bhh[n] + s;
    }
  } else if (i < 65536 + 2048 + 2048) { // pB frags
    int idx = i - 65536 - 2048;
    int ks = idx >> 9, l = (idx >> 3) & 63, j = idx & 7;
    int c = l & 15, kg = l >> 4;
    pBg[idx] = (c < 2) ? f2bf(Whp[c * 128 + ks * 32 + kg * 8 + j]) : (unsigned short)0;
  }
}

// 16 waves (1024 thr), BM=64, grid 512, 1 block/CU at 16 waves => 50% occupancy.
// Wave (wr,wc): wr=row-half (32 rows), wc=col-tile (16 units). Gates i,f weights in
// regs (per-col, shared across wr); gates g,o from LDS. Double-buffered h, 1 barrier/step.
__launch_bounds__(1024, 4)
__global__ void decoder_kernel(const float* __restrict__ lpr,
                               const float* __restrict__ h0,
                               const float* __restrict__ c0,
                               const float* __restrict__ pps,
                               const float* __restrict__ Whp,
                               const float* __restrict__ bhp,
                               const unsigned short* __restrict__ WfReg,
                               const unsigned short* __restrict__ WfGO,
                               const unsigned short* __restrict__ pBg,
                               const float* __restrict__ u,
                               const float* __restrict__ w0,
                               const float* __restrict__ G,
                               float* __restrict__ out_rel,
                               float* __restrict__ out_h) {
  __shared__ unsigned short WgoL[32768];      // 64KB, gates g,o frag order
  __shared__ unsigned short hA[2][BM * 128];  // 2 x 16KB, XOR-swizzled
  __shared__ unsigned short pBL[2048];        // 4KB
  __shared__ float spdL[T_LEN * BM];          // 3KB
  __shared__ float dbuf[BM * 2];
  __shared__ float GL[1024];

  const int tid  = threadIdx.x;
  const int wav  = tid >> 6;
  const int wc   = wav & 7;                   // column-tile
  const int wr   = wav >> 3;                  // row-half
  const int l    = tid & 63;
  const int l15  = l & 15;
  const int lg   = l >> 4;
  const int brow = blockIdx.x * BM;
  const int nh   = wc * 16 + l15;
  const int rowb = wr * 32;
  const int swzA = (l15 & 7) << 4;

  // ---- staging (all coalesced) ----
  short8v bw[2][4];
#pragma unroll
  for (int g = 0; g < 2; ++g)
#pragma unroll
    for (int ks = 0; ks < 4; ++ks)
      bw[g][ks] = *(const short8v*)(WfReg + ((g * 4 + ks) * 512 + wc * 64 + l) * 8);
#pragma unroll
  for (int it = 0; it < 4; ++it) {
    int idx = it * 1024 + tid;
    *(short8v*)(WgoL + idx * 8) = *(const short8v*)(WfGO + idx * 8);
  }
  if (tid < 256) *(short8v*)(pBL + tid * 8) = *(const short8v*)(pBg + tid * 8);
  GL[tid & 1023] = G[tid & 1023];
  if (tid < T_LEN * BM) spdL[tid] = pps[(tid >> 6) * B_N + brow + (tid & 63)];

  float w0r[4], ur[4];
#pragma unroll
  for (int g = 0; g < 4; ++g) { w0r[g] = w0[g * 128 + nh]; ur[g] = u[g * 128 + nh]; }

  f32x4 cst[2];
#pragma unroll
  for (int rt = 0; rt < 2; ++rt)
#pragma unroll
    for (int r = 0; r < 4; ++r)
      cst[rt][r] = c0[(brow + rowb + rt * 16 + lg * 4 + r) * H_N + nh];

  {  // h0 -> hA[0] (bf16, swizzled): 1024 threads cover 64 rows x 16 frags
    int row = tid >> 4, k0 = (tid & 15) * 8;
    const float* src = h0 + (brow + row) * H_N + k0;
    unsigned short tmp[8];
#pragma unroll
    for (int j = 0; j < 8; ++j) tmp[j] = f2bf(src[j]);
    *(short8v*)((char*)&hA[0][0] + ((row * 256 + k0 * 2) ^ ((row & 7) << 4))) = *(short8v*)tmp;
  }
  {  // delta = lpr - h0@Whp^T - bhp  (8 threads per dot, 128 dots)
    int dot = tid >> 3, part = tid & 7;
    int row = dot >> 1, jj = dot & 1;
    float s = 0.f;
    const float* hrow = h0 + (brow + row) * H_N + part * 16;
    const float* wrow = Whp + jj * 128 + part * 16;
#pragma unroll
    for (int k = 0; k < 16; ++k) s += hrow[k] * wrow[k];
    s += __shfl_xor(s, 1); s += __shfl_xor(s, 2); s += __shfl_xor(s, 4);
    if (part == 0) dbuf[dot] = lpr[(brow + row) * 2 + jj] - bhp[jj] - s;
  }
  const float bhpr = (l15 < 2) ? bhp[l15] : 0.f;

  char* rb = (char*)&hA[0][0];
  char* wbuf = (char*)&hA[1][0];

#pragma unroll 1
  for (int t = 0; t < T_LEN; ++t) {
    __syncthreads();   // previous step's h writes (or staging) visible
    f32x4 relC = (f32x4){0.f, 0.f, 0.f, 0.f};

#pragma unroll
    for (int rt = 0; rt < 2; ++rt) {
      f32x4 acc[4];
#pragma unroll
      for (int g = 0; g < 4; ++g) acc[g] = (f32x4){w0r[g], w0r[g], w0r[g], w0r[g]};

#pragma unroll
      for (int ks = 0; ks < 4; ++ks) {
        bf16x8 a = __builtin_bit_cast(bf16x8,
            *(short8v*)(rb + (((rowb + rt * 16 + l15) * 256 + ks * 64 + lg * 16) ^ swzA)));
        bf16x8 bg = __builtin_bit_cast(bf16x8, *(short8v*)(WgoL + (ks * 512 + wc * 64 + l) * 8));
        bf16x8 bo = __builtin_bit_cast(bf16x8, *(short8v*)(WgoL + ((4 + ks) * 512 + wc * 64 + l) * 8));
        acc[0] = __builtin_amdgcn_mfma_f32_16x16x32_bf16(a, __builtin_bit_cast(bf16x8, bw[0][ks]), acc[0], 0, 0, 0);
        acc[1] = __builtin_amdgcn_mfma_f32_16x16x32_bf16(a, __builtin_bit_cast(bf16x8, bw[1][ks]), acc[1], 0, 0, 0);
        acc[2] = __builtin_amdgcn_mfma_f32_16x16x32_bf16(a, bg, acc[2], 0, 0, 0);
        acc[3] = __builtin_amdgcn_mfma_f32_16x16x32_bf16(a, bo, acc[3], 0, 0, 0);
        if (wc == rt && t > 0) {
          bf16x8 pb = __builtin_bit_cast(bf16x8, *(short8v*)(pBL + (ks * 64 + l) * 8));
          relC = __builtin_amdgcn_mfma_f32_16x16x32_bf16(a, pb, relC, 0, 0, 0);
        }
      }
      if (t == 0) {  // rank-2 step-0 correction
#pragma unroll
        for (int r = 0; r < 4; ++r) {
          int row = rowb + rt * 16 + lg * 4 + r;
          float d0 = dbuf[row * 2 + 0], d1 = dbuf[row * 2 + 1];
#pragma unroll
          for (int g = 0; g < 4; ++g)
            acc[g][r] += d0 * GL[(g * 128 + nh) * 2 + 0] + d1 * GL[(g * 128 + nh) * 2 + 1];
        }
      }
      // ---- elementwise for this row-tile ----
#pragma unroll
      for (int r = 0; r < 4; ++r) {
        int row = rowb + rt * 16 + lg * 4 + r;
        float spd = spdL[t * BM + row];
        float gi = __builtin_fmaf(spd, ur[0], acc[0][r]);
        float gf = __builtin_fmaf(spd, ur[1], acc[1][r]);
        float gg = __builtin_fmaf(spd, ur[2], acc[2][r]);
        float go = __builtin_fmaf(spd, ur[3], acc[3][r]);
        float cn = sigm(gf) * cst[rt][r] + sigm(gi) * tanh_(gg);
        cst[rt][r] = cn;
        float h = sigm(go) * tanh_(cn);
        *(unsigned short*)(wbuf + ((row * 256 + nh * 2) ^ ((row & 7) << 4))) = f2bf(h);
        if (t == T_LEN - 1) out_h[(brow + row) * H_N + nh] = h;
      }
    }
    if (wc < 2 && t > 0 && l15 < 2) {
#pragma unroll
      for (int r = 0; r < 4; ++r)
        out_rel[(size_t)(t - 1) * B_N * 2 + (brow + rowb + wc * 16 + lg * 4 + r) * 2 + l15] = relC[r] + bhpr;
    }
    char* tmpp = rb; rb = wbuf; wbuf = tmpp;
  }

  __syncthreads();
  if (wc < 2) {   // epilogue: rel_11 from h_11 (in rb)
    f32x4 relC = (f32x4){0.f, 0.f, 0.f, 0.f};
#pragma unroll
    for (int ks = 0; ks < 4; ++ks) {
      bf16x8 a = __builtin_bit_cast(bf16x8,
          *(short8v*)(rb + (((rowb + wc * 16 + l15) * 256 + ks * 64 + lg * 16) ^ swzA)));
      bf16x8 pb = __builtin_bit_cast(bf16x8, *(short8v*)(pBL + (ks * 64 + l) * 8));
      relC = __builtin_amdgcn_mfma_f32_16x16x32_bf16(a, pb, relC, 0, 0, 0);
    }
    if (l15 < 2) {
#pragma unroll
      for (int r = 0; r < 4; ++r)
        out_rel[(size_t)(T_LEN - 1) * B_N * 2 + (brow + rowb + wc * 16 + lg * 4 + r) * 2 + l15] = relC[r] + bhpr;
    }
  }
}

extern "C" void kernel_launch(void* const* d_in, const int* in_sizes, int n_in,
                              void* d_out, int out_size, void* d_ws, size_t ws_size,
                              hipStream_t stream) {
  const float* lpr  = (const float*)d_in[1];
  const float* h0   = (const float*)d_in[2];
  const float* c0   = (const float*)d_in[3];
  const float* pps  = (const float*)d_in[4];
  const float* W_se = (const float*)d_in[5];
  const float* b_se = (const float*)d_in[6];
  const float* W_ih = (const float*)d_in[7];
  const float* W_hh = (const float*)d_in[8];
  const float* b_ih = (const float*)d_in[9];
  const float* b_hh = (const float*)d_in[10];
  const float* W_hp = (const float*)d_in[11];
  const float* b_hp = (const float*)d_in[12];

  unsigned short* WfReg = (unsigned short*)d_ws;                       // 64KB
  unsigned short* WfGO  = (unsigned short*)((char*)d_ws + 65536);      // 64KB
  unsigned short* pBg   = (unsigned short*)((char*)d_ws + 131072);     // 4KB
  float* u  = (float*)((char*)d_ws + 135168);                          // 2KB
  float* w0 = (float*)((char*)d_ws + 137216);                          // 2KB
  float* G  = (float*)((char*)d_ws + 139264);                          // 4KB

  float* out_rel = (float*)d_out;
  float* out_h   = out_rel + (size_t)T_LEN * B_N * 2;

  hipLaunchKernelGGL(prep_kernel, dim3((65536 + 4096 + 255) / 256), dim3(256), 0, stream,
                     W_ih, W_hh, b_ih, b_hh, W_se, b_se, W_hp, b_hp,
                     WfReg, WfGO, pBg, u, w0, G);
  hipLaunchKernelGGL(decoder_kernel, dim3(B_N / BM), dim3(1024), 0, stream,
                     lpr, h0, c0, pps, W_hp, b_hp, WfReg, WfGO, pBg, u, w0, G,
                     out_rel, out_h);
}

// Round 7
// 217.192 us; speedup vs baseline: 1.0665x; 1.0665x over previous
//
#include <hip/hip_runtime.h>

#define T_LEN 12
#define B_N   32768
#define H_N   128
#define BM    64    // batch rows per block

typedef __attribute__((ext_vector_type(8))) __bf16 bf16x8;
typedef __attribute__((ext_vector_type(8))) short  short8v;
typedef __attribute__((ext_vector_type(4))) float  f32x4;

__device__ __forceinline__ unsigned short f2bf(float f) {
  unsigned int u = __builtin_bit_cast(unsigned int, f);
  u += 0x7fffu + ((u >> 16) & 1u);
  return (unsigned short)(u >> 16);
}
// gates i,f,o pre-scaled by -log2(e); gate g pre-scaled by +2*log2(e)
__device__ __forceinline__ float sigm_p(float x) {
  return __builtin_amdgcn_rcpf(1.f + __builtin_amdgcn_exp2f(x));
}
__device__ __forceinline__ float tanh_p(float x) {
  return __builtin_fmaf(-2.f, __builtin_amdgcn_rcpf(__builtin_amdgcn_exp2f(x) + 1.f), 1.f);
}
__device__ __forceinline__ float tanh_c(float x) {   // raw argument
  return tanh_p(2.8853900817779268f * x);
}

// Fused weights in MFMA B-fragment order, with per-gate logistic scales baked in.
//   WfA[g][ks][512][8]: (Whh + (Wih@Wse01)@Whp) * SCL[g]   (bf16)
//   G[512][2] = Wih@Wse01 * SCL ; u[512] = Wih@wse2 * SCL ;
//   w0[512] = (bih+bhh+Wih@bse+G_raw@bhp) * SCL
//   pBg: B-frags of Whp^T (cols 0,1 real, rest zero), unscaled
__global__ void prep_kernel(const float* __restrict__ Wih, const float* __restrict__ Whh,
                            const float* __restrict__ bih, const float* __restrict__ bhh,
                            const float* __restrict__ Wse, const float* __restrict__ bse,
                            const float* __restrict__ Whp, const float* __restrict__ bhp,
                            unsigned short* __restrict__ WfA, unsigned short* __restrict__ pBg,
                            float* __restrict__ u, float* __restrict__ w0,
                            float* __restrict__ G) {
  const float SCL[4] = {-1.4426950408889634f, -1.4426950408889634f,
                         2.8853900817779268f, -1.4426950408889634f};
  int i = blockIdx.x * 256 + threadIdx.x;
  if (i < 65536) {                      // one fused Wf element (row,k)
    int row = i >> 7, k = i & 127;
    float s = Whh[row * 128 + k];
    float wh0 = Whp[k], wh1 = Whp[128 + k];
    for (int e = 0; e < 64; ++e)
      s += Wih[row * 64 + e] * (Wse[e * 3 + 0] * wh0 + Wse[e * 3 + 1] * wh1);
    int g = row >> 7, unit = row & 127, w = unit >> 4, l15 = unit & 15;
    int ks = k >> 5, kg = (k >> 3) & 3, j = k & 7, l = kg * 16 + l15;
    WfA[((g * 4 + ks) * 512 + w * 64 + l) * 8 + j] = f2bf(s * SCL[g]);
  } else if (i < 65536 + 2048) {        // u / w0 / G (all gate-scaled)
    int j = i - 65536;
    int n = j >> 2, which = j & 3, g = n >> 7;
    float s = 0.f;
    if (which < 2) {
      for (int e = 0; e < 64; ++e) s += Wih[n * 64 + e] * Wse[e * 3 + which];
      G[n * 2 + which] = s * SCL[g];
    } else if (which == 2) {
      for (int e = 0; e < 64; ++e) s += Wih[n * 64 + e] * Wse[e * 3 + 2];
      u[n] = s * SCL[g];
    } else {
      for (int e = 0; e < 64; ++e)
        s += Wih[n * 64 + e] * (bse[e] + Wse[e * 3 + 0] * bhp[0] + Wse[e * 3 + 1] * bhp[1]);
      w0[n] = (bih[n] + bhh[n] + s) * SCL[g];
    }
  } else if (i < 65536 + 2048 + 2048) { // pB frags (unscaled)
    int idx = i - 65536 - 2048;
    int ks = idx >> 9, l = (idx >> 3) & 63, j = idx & 7;
    int c = l & 15, kg = l >> 4;
    pBg[idx] = (c < 2) ? f2bf(Whp[c * 128 + ks * 32 + kg * 8 + j]) : (unsigned short)0;
  }
}

// 16 waves (1024 thr), BM=64, grid 512, 1 block/CU (LDS-capped), 4 waves/EU.
// ALL gate weights in LDS (128KB) => ~55 arch VGPRs/lane, no spill at the
// 128-unified/wave budget. Single h buffer, 2 barriers/step.
// Wave (wr,wc): wr = row-half (32 rows), wc = col-tile (16 hidden units).
__launch_bounds__(1024, 4)
__global__ void decoder_kernel(const float* __restrict__ lpr,
                               const float* __restrict__ h0,
                               const float* __restrict__ c0,
                               const float* __restrict__ pps,
                               const float* __restrict__ Whp,
                               const float* __restrict__ bhp,
                               const unsigned short* __restrict__ WfA,
                               const unsigned short* __restrict__ pBg,
                               const float* __restrict__ u,
                               const float* __restrict__ w0,
                               const float* __restrict__ G,
                               float* __restrict__ out_rel,
                               float* __restrict__ out_h) {
  __shared__ unsigned short WfL[65536];       // 128KB: all 4 gates, frag order
  __shared__ unsigned short hA[BM * 128];     // 16KB, XOR-swizzled, single buffer
  __shared__ unsigned short pBL[2048];        // 4KB
  __shared__ float spdL[T_LEN * BM];          // 3KB
  __shared__ float dbuf[BM * 2];              // 0.5KB
  __shared__ float GL[1024];                  // 4KB

  const int tid  = threadIdx.x;
  const int wav  = tid >> 6;
  const int wc   = wav & 7;                   // column-tile (16 units)
  const int wr   = wav >> 3;                  // row-half (32 rows)
  const int l    = tid & 63;
  const int l15  = l & 15;
  const int lg   = l >> 4;
  const int brow = blockIdx.x * BM;
  const int nh   = wc * 16 + l15;
  const int rowb = wr * 32;
  const int swzA = (l15 & 7) << 4;
  char* hB = (char*)hA;

  // ---- staging (all coalesced) ----
#pragma unroll
  for (int it = 0; it < 8; ++it) {
    int idx = it * 1024 + tid;
    *(short8v*)(WfL + idx * 8) = *(const short8v*)(WfA + idx * 8);
  }
  if (tid < 256) *(short8v*)(pBL + tid * 8) = *(const short8v*)(pBg + tid * 8);
  GL[tid & 1023] = G[tid & 1023];
  if (tid < T_LEN * BM) spdL[tid] = pps[(tid >> 6) * B_N + brow + (tid & 63)];

  float w0r[4], ur[4];
#pragma unroll
  for (int g = 0; g < 4; ++g) { w0r[g] = w0[g * 128 + nh]; ur[g] = u[g * 128 + nh]; }

  f32x4 cst[2];
#pragma unroll
  for (int rt = 0; rt < 2; ++rt)
#pragma unroll
    for (int r = 0; r < 4; ++r)
      cst[rt][r] = c0[(brow + rowb + rt * 16 + lg * 4 + r) * H_N + nh];

  {  // h0 -> hA (bf16, swizzled): 1024 threads cover 64 rows x 16 chunks
    int row = tid >> 4, k0 = (tid & 15) * 8;
    const float* src = h0 + (brow + row) * H_N + k0;
    unsigned short tmp[8];
#pragma unroll
    for (int j = 0; j < 8; ++j) tmp[j] = f2bf(src[j]);
    *(short8v*)(hB + ((row * 256 + k0 * 2) ^ ((row & 7) << 4))) = *(short8v*)tmp;
  }
  {  // delta = lpr - h0@Whp^T - bhp  (8 threads per dot, 128 dots)
    int dot = tid >> 3, part = tid & 7;
    int row = dot >> 1, jj = dot & 1;
    float s = 0.f;
    const float* hrow = h0 + (brow + row) * H_N + part * 16;
    const float* wrow = Whp + jj * 128 + part * 16;
#pragma unroll
    for (int k = 0; k < 16; ++k) s += hrow[k] * wrow[k];
    s += __shfl_xor(s, 1); s += __shfl_xor(s, 2); s += __shfl_xor(s, 4);
    if (part == 0) dbuf[dot] = lpr[(brow + row) * 2 + jj] - bhp[jj] - s;
  }
  const float bhpr = (l15 < 2) ? bhp[l15] : 0.f;

#pragma unroll 1
  for (int t = 0; t < T_LEN; ++t) {
    __syncthreads();   // (1) h writes from previous step visible

    // ================= phase A: MFMA =================
    f32x4 acc[4][2];
#pragma unroll
    for (int g = 0; g < 4; ++g)
#pragma unroll
      for (int rt = 0; rt < 2; ++rt)
        acc[g][rt] = (f32x4){w0r[g], w0r[g], w0r[g], w0r[g]};
    f32x4 relC = (f32x4){0.f, 0.f, 0.f, 0.f};

#pragma unroll
    for (int ks = 0; ks < 4; ++ks) {
      bf16x8 a0 = __builtin_bit_cast(bf16x8,
          *(short8v*)(hB + (((rowb + l15) * 256 + ks * 64 + lg * 16) ^ swzA)));
      bf16x8 a1 = __builtin_bit_cast(bf16x8,
          *(short8v*)(hB + (((rowb + 16 + l15) * 256 + ks * 64 + lg * 16) ^ swzA)));
      bf16x8 b0 = __builtin_bit_cast(bf16x8, *(short8v*)(WfL + ((0 * 4 + ks) * 512 + wc * 64 + l) * 8));
      bf16x8 b1 = __builtin_bit_cast(bf16x8, *(short8v*)(WfL + ((1 * 4 + ks) * 512 + wc * 64 + l) * 8));
      bf16x8 b2 = __builtin_bit_cast(bf16x8, *(short8v*)(WfL + ((2 * 4 + ks) * 512 + wc * 64 + l) * 8));
      bf16x8 b3 = __builtin_bit_cast(bf16x8, *(short8v*)(WfL + ((3 * 4 + ks) * 512 + wc * 64 + l) * 8));
      acc[0][0] = __builtin_amdgcn_mfma_f32_16x16x32_bf16(a0, b0, acc[0][0], 0, 0, 0);
      acc[0][1] = __builtin_amdgcn_mfma_f32_16x16x32_bf16(a1, b0, acc[0][1], 0, 0, 0);
      acc[1][0] = __builtin_amdgcn_mfma_f32_16x16x32_bf16(a0, b1, acc[1][0], 0, 0, 0);
      acc[1][1] = __builtin_amdgcn_mfma_f32_16x16x32_bf16(a1, b1, acc[1][1], 0, 0, 0);
      acc[2][0] = __builtin_amdgcn_mfma_f32_16x16x32_bf16(a0, b2, acc[2][0], 0, 0, 0);
      acc[2][1] = __builtin_amdgcn_mfma_f32_16x16x32_bf16(a1, b2, acc[2][1], 0, 0, 0);
      acc[3][0] = __builtin_amdgcn_mfma_f32_16x16x32_bf16(a0, b3, acc[3][0], 0, 0, 0);
      acc[3][1] = __builtin_amdgcn_mfma_f32_16x16x32_bf16(a1, b3, acc[3][1], 0, 0, 0);
      if (wc < 2 && t > 0) {
        bf16x8 pb = __builtin_bit_cast(bf16x8, *(short8v*)(pBL + (ks * 64 + l) * 8));
        relC = __builtin_amdgcn_mfma_f32_16x16x32_bf16(wc == 0 ? a0 : a1, pb, relC, 0, 0, 0);
      }
    }
    if (wc < 2 && t > 0 && l15 < 2) {
#pragma unroll
      for (int r = 0; r < 4; ++r)
        out_rel[(size_t)(t - 1) * B_N * 2 + (brow + rowb + wc * 16 + lg * 4 + r) * 2 + l15] = relC[r] + bhpr;
    }

    __syncthreads();   // (2) all hA reads complete before overwrite

    // ================= phase B: elementwise =================
#pragma unroll
    for (int rt = 0; rt < 2; ++rt) {
      const f32x4 spdv = *(const f32x4*)(spdL + t * BM + rowb + rt * 16 + lg * 4);
      if (t == 0) {  // rank-2 step-0 correction (uniform branch, runs once)
#pragma unroll
        for (int r = 0; r < 4; ++r) {
          int row = rowb + rt * 16 + lg * 4 + r;
          float d0 = dbuf[row * 2 + 0], d1 = dbuf[row * 2 + 1];
#pragma unroll
          for (int g = 0; g < 4; ++g)
            acc[g][rt][r] += d0 * GL[(g * 128 + nh) * 2 + 0] + d1 * GL[(g * 128 + nh) * 2 + 1];
        }
      }
#pragma unroll
      for (int r = 0; r < 4; ++r) {
        int row = rowb + rt * 16 + lg * 4 + r;
        float spd = spdv[r];
        float gi = __builtin_fmaf(spd, ur[0], acc[0][rt][r]);
        float gf = __builtin_fmaf(spd, ur[1], acc[1][rt][r]);
        float gg = __builtin_fmaf(spd, ur[2], acc[2][rt][r]);
        float go = __builtin_fmaf(spd, ur[3], acc[3][rt][r]);
        float cn = sigm_p(gf) * cst[rt][r] + sigm_p(gi) * tanh_p(gg);
        cst[rt][r] = cn;
        float h = sigm_p(go) * tanh_c(cn);
        *(unsigned short*)(hB + ((row * 256 + nh * 2) ^ ((row & 7) << 4))) = f2bf(h);
        if (t == T_LEN - 1) out_h[(brow + row) * H_N + nh] = h;
      }
    }
  }

  __syncthreads();
  if (wc < 2) {   // epilogue: rel_11 from h_11
    f32x4 relC = (f32x4){0.f, 0.f, 0.f, 0.f};
#pragma unroll
    for (int ks = 0; ks < 4; ++ks) {
      bf16x8 a = __builtin_bit_cast(bf16x8,
          *(short8v*)(hB + (((rowb + wc * 16 + l15) * 256 + ks * 64 + lg * 16) ^ swzA)));
      bf16x8 pb = __builtin_bit_cast(bf16x8, *(short8v*)(pBL + (ks * 64 + l) * 8));
      relC = __builtin_amdgcn_mfma_f32_16x16x32_bf16(a, pb, relC, 0, 0, 0);
    }
    if (l15 < 2) {
#pragma unroll
      for (int r = 0; r < 4; ++r)
        out_rel[(size_t)(T_LEN - 1) * B_N * 2 + (brow + rowb + wc * 16 + lg * 4 + r) * 2 + l15] = relC[r] + bhpr;
    }
  }
}

extern "C" void kernel_launch(void* const* d_in, const int* in_sizes, int n_in,
                              void* d_out, int out_size, void* d_ws, size_t ws_size,
                              hipStream_t stream) {
  const float* lpr  = (const float*)d_in[1];
  const float* h0   = (const float*)d_in[2];
  const float* c0   = (const float*)d_in[3];
  const float* pps  = (const float*)d_in[4];
  const float* W_se = (const float*)d_in[5];
  const float* b_se = (const float*)d_in[6];
  const float* W_ih = (const float*)d_in[7];
  const float* W_hh = (const float*)d_in[8];
  const float* b_ih = (const float*)d_in[9];
  const float* b_hh = (const float*)d_in[10];
  const float* W_hp = (const float*)d_in[11];
  const float* b_hp = (const float*)d_in[12];

  unsigned short* WfA = (unsigned short*)d_ws;                         // 128KB
  unsigned short* pBg = (unsigned short*)((char*)d_ws + 131072);       // 4KB
  float* u  = (float*)((char*)d_ws + 135168);                          // 2KB
  float* w0 = (float*)((char*)d_ws + 137216);                          // 2KB
  float* G  = (float*)((char*)d_ws + 139264);                          // 4KB

  float* out_rel = (float*)d_out;
  float* out_h   = out_rel + (size_t)T_LEN * B_N * 2;

  hipLaunchKernelGGL(prep_kernel, dim3((65536 + 4096 + 255) / 256), dim3(256), 0, stream,
                     W_ih, W_hh, b_ih, b_hh, W_se, b_se, W_hp, b_hp,
                     WfA, pBg, u, w0, G);
  hipLaunchKernelGGL(decoder_kernel, dim3(B_N / BM), dim3(1024), 0, stream,
                     lpr, h0, c0, pps, W_hp, b_hp, WfA, pBg, u, w0, G,
                     out_rel, out_h);
}